// Round 10
// baseline (91.860 us; speedup 1.0000x reference)
//
#include <hip/hip_runtime.h>
#include <math.h>

#define HH 512
#define WW 1024
#define RR 5
#define KK 11
#define TOPK 200

// diagnostic multipliers (all kernel bodies idempotent)
#define VOTE_REPS 8
#define NMS_REPS 16
#define IS_REPS 14

// ---- vote tile: 64 wide x 8 tall, 256 threads, 2 output rows per thread
// grid 1024 blocks = 4 blocks/CU -> 16 waves/CU
#define BW 64
#define BH 8
#define TT 2
#define SROWS (BH + 10)   // 18 staged rows
#define SCOLS (BW + 10)   // 74 staged cols

// ---- nms tile: 64 wide x 16 tall, 512 blocks (2/CU), 4 output rows/thread
#define MAXPB 96          // 7x7 minima in 64x16 tile <= 17*5=85 (tie-free)
#define NBUCK 512         // nms grid size
#define CAP 1536          // selection LDS compaction cap

// ws layout (bytes):
// [0 .. 2047]      : counts int[NBUCK]
// [2048 ..)        : vote float[H*W]
// [+4*HW ..)       : gcv float[NBUCK*MAXPB]
// [+4*NB*MPB ..)   : gci int[NBUCK*MAXPB]

__global__ __launch_bounds__(256) void vote_kernel(const float* __restrict__ cr,
                                                   float* __restrict__ vote) {
    __shared__ float2 s[SROWS][SCOLS + 2];   // row stride 76 float2
    const int tid = threadIdx.x;
    const int bx = blockIdx.x * BW, by = blockIdx.y * BH;

    #pragma unroll 1
    for (int rep = 0; rep < VOTE_REPS; ++rep) {
        // Stage cr (18 x 74) region, origin (by-5, bx-5), zero-padded.
        for (int l = tid; l < SROWS * SCOLS; l += 256) {
            int r = l / SCOLS, c = l % SCOLS;
            int gy = by - 5 + r, gx = bx - 5 + c;
            bool ok = (gy >= 0) && (gy < HH) && (gx >= 0) && (gx < WW);
            float vx = ok ? cr[gy * WW + gx] : 0.0f;
            float vy = ok ? cr[HH * WW + gy * WW + gx] : 0.0f;
            s[r][c] = make_float2(vx, vy);
        }
        __syncthreads();

        const int x = tid & 63;        // 0..63 within tile
        const int yt = tid >> 6;       // 0..3 -> output rows yt*2, yt*2+1
        // 2 accumulator chains per output row (reassociated: safe, ~1e-5
        // perturbation vs ~0.3 margin to CENTER_THRESH; NMS equality only
        // compares values computed with identical op order everywhere).
        float a[TT] = {0.f, 0.f};
        float b[TT] = {0.f, 0.f};

        #pragma unroll
        for (int rr = 0; rr < TT + 10; ++rr) {          // staged row offset
            #pragma unroll
            for (int ix = 0; ix < KK; ++ix) {
                const int ox = ix - 5;
                bool any = false;
                #pragma unroll
                for (int t = 0; t < TT; ++t) {
                    const int oy = rr - 5 - t;
                    if (oy >= -RR && oy <= RR && ox * ox + oy * oy <= RR * RR) any = true;
                }
                if (!any) continue;                      // compile-time elision
                float2 v = s[yt * TT + rr][x + ix];
                float dx = (float)ox - v.x;              // dx^2 CSE'd across t
                float dx2 = dx * dx;
                #pragma unroll
                for (int t = 0; t < TT; ++t) {
                    const int oy = rr - 5 - t;
                    if (oy >= -RR && oy <= RR && ox * ox + oy * oy <= RR * RR) {
                        float dy = (float)oy - v.y;
                        float sv = __builtin_amdgcn_sqrtf(fmaf(dy, dy, dx2));
                        if (ix & 1) b[t] += sv; else a[t] += sv;
                    }
                }
            }
        }
        const int y0 = by + yt * TT;
        #pragma unroll
        for (int t = 0; t < TT; ++t)
            vote[(y0 + t) * WW + bx + x] = (a[t] + b[t]) / 81.0f + 1.0f;
        __syncthreads();   // protect s[][] before next rep re-stages
    }
}

// Separable 7x7 min-pool NMS over 64x16 tiles (512 blocks, 2/CU);
// deterministic per-block buckets (no global atomics, no init, replay-safe).
__global__ __launch_bounds__(256) void nms_kernel(const float* __restrict__ vote,
                                                  float* __restrict__ gcv,
                                                  int* __restrict__ gci,
                                                  int* __restrict__ counts, float ct) {
    __shared__ int lcnt;
    __shared__ float lval[MAXPB];
    __shared__ int lidx[MAXPB];
    const int tid = threadIdx.x;
    const int x = blockIdx.x * 64 + (tid & 63);
    const int g = tid >> 6;                    // 0..3
    const int y0 = blockIdx.y * 16 + g * 4;    // 4 output rows per thread

    int xc[7];
    #pragma unroll
    for (int d = 0; d < 7; ++d) xc[d] = min(max(x + d - 3, 0), WW - 1);

    #pragma unroll 1
    for (int rep = 0; rep < NMS_REPS; ++rep) {
        if (tid == 0) lcnt = 0;
        __syncthreads();

        float r10[10], ctr[4];
        #pragma unroll
        for (int j = 0; j < 10; ++j) {
            int yy = min(max(y0 + j - 3, 0), HH - 1);   // clamp == inf-pad
            const float* row = vote + yy * WW;
            float m0 = fminf(row[xc[0]], row[xc[1]]);
            float m1 = fminf(row[xc[2]], row[xc[3]]);
            float m2 = fminf(row[xc[4]], row[xc[5]]);
            float m3 = row[xc[6]];
            if (j >= 3 && j < 7) ctr[j - 3] = row[xc[3]];   // xc[3]==x
            r10[j] = fminf(fminf(m0, m1), fminf(m2, m3));
        }
        float p[9], q[7];
        #pragma unroll
        for (int j = 0; j < 9; ++j) p[j] = fminf(r10[j], r10[j + 1]);
        #pragma unroll
        for (int j = 0; j < 7; ++j) q[j] = fminf(p[j], p[j + 2]);
        #pragma unroll
        for (int t = 0; t < 4; ++t) {
            float m = fminf(q[t], q[t + 3]);
            float v = ctr[t];
            if (v == m && v < ct) {
                int sp = atomicAdd(&lcnt, 1);   // LDS atomic, block-local
                if (sp < MAXPB) { lval[sp] = v; lidx[sp] = (y0 + t) * WW + x; }
            }
        }
        __syncthreads();

        int bkt = blockIdx.y * gridDim.x + blockIdx.x;
        int cnt = min(lcnt, MAXPB);
        if (tid == 0) counts[bkt] = cnt;
        for (int i = tid; i < cnt; i += 256) {
            gcv[bkt * MAXPB + i] = lval[i];
            gci[bkt * MAXPB + i] = lidx[i];
        }
        __syncthreads();
    }
}

// Bucket compaction (pair-compressed scan over 512 buckets) + replicated
// selection (cheap when M small) + instance assignment.
__global__ __launch_bounds__(256) void inst_select_kernel(const float* __restrict__ fg,
                                                          const float* __restrict__ cr,
                                                          const float* __restrict__ gcv,
                                                          const int* __restrict__ gci,
                                                          const int* __restrict__ counts,
                                                          float* __restrict__ out) {
    __shared__ int s_pre[256];
    __shared__ float s_cv[CAP];
    __shared__ int s_ci[CAP];
    __shared__ float bv[256];
    __shared__ int bi[256];
    __shared__ int s_idx[TOPK];
    __shared__ float s_val[TOPK];
    __shared__ float s_selx[TOPK];
    __shared__ float s_sely[TOPK];
    const int tid = threadIdx.x;

    #pragma unroll 1
    for (int rep = 0; rep < IS_REPS; ++rep) {
        // ---- compact buckets into LDS: each thread owns 2 buckets ----
        int c0 = counts[2 * tid];
        int c1 = counts[2 * tid + 1];
        s_pre[tid] = c0 + c1;
        __syncthreads();
        #pragma unroll
        for (int off = 1; off < 256; off <<= 1) {
            int add = (tid >= off) ? s_pre[tid - off] : 0;
            __syncthreads();
            s_pre[tid] += add;
            __syncthreads();
        }
        int total = s_pre[255];
        int M = min(total, CAP);
        int inc = s_pre[tid];
        int base0 = inc - c0 - c1;
        int base1 = inc - c1;
        for (int j = 0; j < c0; ++j) {
            int p = base0 + j;
            if (p < CAP) { s_cv[p] = gcv[(2 * tid) * MAXPB + j]; s_ci[p] = gci[(2 * tid) * MAXPB + j]; }
        }
        for (int j = 0; j < c1; ++j) {
            int p = base1 + j;
            if (p < CAP) { s_cv[p] = gcv[(2 * tid + 1) * MAXPB + j]; s_ci[p] = gci[(2 * tid + 1) * MAXPB + j]; }
        }
        __syncthreads();

        const int Mtop = (M < TOPK) ? M : TOPK;

        // k-th smallest by (val, idx) lexicographic = min over entries
        // strictly greater than the previous pick (jax top_k tie-break).
        float lastv = -INFINITY;
        int lasti = -1;
        for (int k = 0; k < Mtop; ++k) {
            float bestv = INFINITY;
            int besti = 0x7fffffff;
            for (int j = tid; j < M; j += 256) {
                float cvj = s_cv[j];
                int cij = s_ci[j];
                if (cvj > lastv || (cvj == lastv && cij > lasti)) {
                    if (cvj < bestv || (cvj == bestv && cij < besti)) { bestv = cvj; besti = cij; }
                }
            }
            bv[tid] = bestv; bi[tid] = besti;
            __syncthreads();
            for (int s = 128; s > 0; s >>= 1) {
                if (tid < s) {
                    float ov = bv[tid + s]; int oi = bi[tid + s];
                    if (ov < bv[tid] || (ov == bv[tid] && oi < bi[tid])) { bv[tid] = ov; bi[tid] = oi; }
                }
                __syncthreads();
            }
            lastv = bv[0]; lasti = bi[0];
            if (tid == 0) { s_val[k] = lastv; s_idx[k] = lasti; }
            __syncthreads();
        }

        // Parallel fill of remaining slots with smallest non-candidate
        // indices (non-candidates tie at -inf in top_k(-cand): ascending
        // index). rank r index = fixed point of g = r + #{ci <= g}.
        for (int k = Mtop + tid; k < TOPK; k += 256) {
            int r = k - Mtop;
            int g = r, prev = -1;
            while (g != prev) {
                prev = g;
                int cnt2 = 0;
                for (int j = 0; j < M; ++j) cnt2 += (s_ci[j] <= g) ? 1 : 0;
                g = r + cnt2;
            }
            s_idx[k] = g;
            s_val[k] = INFINITY;
        }
        __syncthreads();

        for (int k = tid; k < TOPK; k += 256) {
            int idx = s_idx[k];
            s_sely[k] = (float)(idx >> 10);       // idx / W
            s_selx[k] = (float)(idx & (WW - 1));  // idx % W
        }
        __syncthreads();

        // block 0 writes coords + cerr outputs
        if (blockIdx.x == 0) {
            for (int k = tid; k < TOPK; k += 256) {
                out[HH * WW + 2 * k]     = s_sely[k];
                out[HH * WW + 2 * k + 1] = s_selx[k];
                out[HH * WW + 2 * TOPK + k] = (k < Mtop) ? s_val[k] : 0.0f;
            }
        }

        // ---- instance assignment: 4 pixels per thread, float4 I/O ----
        int idx4 = blockIdx.x * 256 + tid;     // float4 index
        float4 o = make_float4(0.f, 0.f, 0.f, 0.f);
        if (M > 0) {
            int pix0 = idx4 * 4;
            int y = pix0 >> 10;
            float4 f = ((const float4*)fg)[idx4];
            float4 cx0 = ((const float4*)cr)[idx4];
            float4 cy0 = ((const float4*)(cr + HH * WW))[idx4];
            float fgv[4] = {f.x, f.y, f.z, f.w};
            float crx[4] = {cx0.x, cx0.y, cx0.z, cx0.w};
            float cry[4] = {cy0.x, cy0.y, cy0.z, cy0.w};
            float res[4];
            #pragma unroll
            for (int t = 0; t < 4; ++t) {
                res[t] = 0.f;
                if (fgv[t] >= 0.5f) {
                    int x = (pix0 + t) & (WW - 1);
                    float px = (float)(x + 1) - crx[t];
                    float py = (float)(y + 1) - cry[t];
                    float best = INFINITY;
                    int bk = 0;
                    for (int k = 0; k < Mtop; ++k) {
                        float ddx = px - s_selx[k];
                        float ddy = py - s_sely[k];
                        float d = ddx * ddx + ddy * ddy;
                        if (d < best) { best = d; bk = k; }  // first-occurrence
                    }
                    res[t] = (float)(bk + 1);
                }
            }
            o = make_float4(res[0], res[1], res[2], res[3]);
        }
        ((float4*)out)[idx4] = o;
        __syncthreads();   // protect shared state before next rep
    }
}

extern "C" void kernel_launch(void* const* d_in, const int* in_sizes, int n_in,
                              void* d_out, int out_size, void* d_ws, size_t ws_size,
                              hipStream_t stream) {
    const float* fg = (const float*)d_in[0];
    const float* cr = (const float*)d_in[1];
    float* out = (float*)d_out;

    char* ws = (char*)d_ws;
    int* counts = (int*)ws;
    float* vote = (float*)(ws + 2048);
    float* gcv = (float*)(ws + 2048 + 4 * HH * WW);
    int* gci = (int*)(ws + 2048 + 4 * HH * WW + 4 * NBUCK * MAXPB);

    // CENTER_THRESH = mean circle distance + 0.5
    double s = 0.0;
    int n = 0;
    for (int iy = 0; iy < KK; ++iy)
        for (int ix = 0; ix < KK; ++ix) {
            double dx = ix - RR, dy = iy - RR;
            double d = sqrt(dx * dx + dy * dy);
            if (d <= (double)RR) { s += d; n++; }
        }
    float ct = (float)(s / n + 0.5);

    dim3 vgrid(WW / BW, HH / BH);        // 16 x 64 = 1024 blocks
    vote_kernel<<<vgrid, 256, 0, stream>>>(cr, vote);
    dim3 ngrid(WW / 64, HH / 16);        // 16 x 32 = 512 blocks
    nms_kernel<<<ngrid, 256, 0, stream>>>(vote, gcv, gci, counts, ct);
    inst_select_kernel<<<(HH * WW / 4) / 256, 256, 0, stream>>>(fg, cr, gcv, gci, counts, out);
}

// Round 11
// 25.226 us; speedup vs baseline: 3.6415x; 3.6415x over previous
//
#include <hip/hip_runtime.h>
#include <math.h>

#define HH 512
#define WW 1024
#define RR 5
#define KK 11
#define TOPK 200

typedef float v2f __attribute__((ext_vector_type(2)));

// ---- vote tile: 64 wide x 8 tall, 256 threads, 2 output rows per thread
// grid 1024 blocks = 4 blocks/CU -> 16 waves/CU (measured: VALUBusy 80%)
#define BW 64
#define BH 8
#define TT 2
#define SROWS (BH + 10)   // 18 staged rows
#define SCOLS (BW + 10)   // 74 staged cols

// ---- nms tile: 64 wide x 16 tall, 512 blocks (2/CU), 4 output rows/thread
#define MAXPB 96          // 7x7 minima in 64x16 tile <= 17*5=85 (tie-free)
#define NBUCK 512         // nms grid size
#define CAP 1536          // selection LDS compaction cap

// ws layout (bytes):
// [0 .. 2047]      : counts int[NBUCK]
// [2048 ..)        : vote float[H*W]
// [+4*HW ..)       : gcv float[NBUCK*MAXPB]
// [+4*NB*MPB ..)   : gci int[NBUCK*MAXPB]

__device__ __forceinline__ constexpr bool circ(int ox, int oy) {
    return oy >= -RR && oy <= RR && ox * ox + oy * oy <= RR * RR;
}

__global__ __launch_bounds__(256) void vote_kernel(const float* __restrict__ cr,
                                                   float* __restrict__ vote) {
    __shared__ float2 s[SROWS][SCOLS + 2];   // row stride 76 float2
    const int tid = threadIdx.x;
    const int bx = blockIdx.x * BW, by = blockIdx.y * BH;

    // Stage cr (18 x 74) region, origin (by-5, bx-5), zero-padded.
    for (int l = tid; l < SROWS * SCOLS; l += 256) {
        int r = l / SCOLS, c = l % SCOLS;
        int gy = by - 5 + r, gx = bx - 5 + c;
        bool ok = (gy >= 0) && (gy < HH) && (gx >= 0) && (gx < WW);
        float vx = ok ? cr[gy * WW + gx] : 0.0f;
        float vy = ok ? cr[HH * WW + gy * WW + gx] : 0.0f;
        s[r][c] = make_float2(vx, vy);
    }
    __syncthreads();

    const int x = tid & 63;        // 0..63 within tile
    const int yt = tid >> 6;       // 0..3 -> output rows yt*2, yt*2+1
    // Packed-FP32 formulation: both-valid (t0,t1) samples run as v2f ops
    // (v_pk_sub/fma/add on gfx950); single-valid edges stay scalar.
    // Reassociated sums: safe — ~1e-5 perturbation vs ~0.3 margin to
    // CENTER_THRESH; NMS equality only compares self-consistent values.
    v2f pA = {0.f, 0.f}, pB = {0.f, 0.f};   // both-valid chains (ix parity)
    float s0 = 0.f, s1 = 0.f;               // single-valid chains per t

    #pragma unroll
    for (int rr = 0; rr < TT + 10; ++rr) {          // staged row offset 0..11
        #pragma unroll
        for (int ix = 0; ix < KK; ++ix) {
            const int ox = ix - 5;
            const int oy0 = rr - 5, oy1 = rr - 6;
            const bool v0 = circ(ox, oy0), v1 = circ(ox, oy1);
            if (!v0 && !v1) continue;                // compile-time elision
            float2 v = s[yt * TT + rr][x + ix];
            float dx = (float)ox - v.x;
            float dx2 = dx * dx;
            if (v0 && v1) {
                v2f dy = {(float)oy0 - v.y, (float)oy1 - v.y};
                v2f dx22 = {dx2, dx2};
                v2f r = dy * dy + dx22;              // -> v_pk_fma_f32
                v2f sv = {__builtin_amdgcn_sqrtf(r.x), __builtin_amdgcn_sqrtf(r.y)};
                if (ix & 1) pB += sv; else pA += sv; // -> v_pk_add_f32
            } else if (v0) {
                float dy = (float)oy0 - v.y;
                s0 += __builtin_amdgcn_sqrtf(fmaf(dy, dy, dx2));
            } else {
                float dy = (float)oy1 - v.y;
                s1 += __builtin_amdgcn_sqrtf(fmaf(dy, dy, dx2));
            }
        }
    }
    const int y0 = by + yt * TT;
    vote[y0 * WW + bx + x]       = (pA.x + pB.x + s0) / 81.0f + 1.0f;
    vote[(y0 + 1) * WW + bx + x] = (pA.y + pB.y + s1) / 81.0f + 1.0f;
}

// Separable 7x7 min-pool NMS over 64x16 tiles (512 blocks, 2/CU);
// deterministic per-block buckets (no global atomics, no init, replay-safe).
__global__ __launch_bounds__(256) void nms_kernel(const float* __restrict__ vote,
                                                  float* __restrict__ gcv,
                                                  int* __restrict__ gci,
                                                  int* __restrict__ counts, float ct) {
    __shared__ int lcnt;
    __shared__ float lval[MAXPB];
    __shared__ int lidx[MAXPB];
    const int tid = threadIdx.x;
    const int x = blockIdx.x * 64 + (tid & 63);
    const int g = tid >> 6;                    // 0..3
    const int y0 = blockIdx.y * 16 + g * 4;    // 4 output rows per thread

    if (tid == 0) lcnt = 0;
    __syncthreads();

    int xc[7];
    #pragma unroll
    for (int d = 0; d < 7; ++d) xc[d] = min(max(x + d - 3, 0), WW - 1);

    float r10[10], ctr[4];
    #pragma unroll
    for (int j = 0; j < 10; ++j) {
        int yy = min(max(y0 + j - 3, 0), HH - 1);   // clamp == inf-pad for min
        const float* row = vote + yy * WW;
        float m0 = fminf(row[xc[0]], row[xc[1]]);
        float m1 = fminf(row[xc[2]], row[xc[3]]);
        float m2 = fminf(row[xc[4]], row[xc[5]]);
        float m3 = row[xc[6]];
        if (j >= 3 && j < 7) ctr[j - 3] = row[xc[3]];   // xc[3]==x
        r10[j] = fminf(fminf(m0, m1), fminf(m2, m3));
    }
    float p[9], q[7];
    #pragma unroll
    for (int j = 0; j < 9; ++j) p[j] = fminf(r10[j], r10[j + 1]);
    #pragma unroll
    for (int j = 0; j < 7; ++j) q[j] = fminf(p[j], p[j + 2]);
    #pragma unroll
    for (int t = 0; t < 4; ++t) {
        float m = fminf(q[t], q[t + 3]);
        float v = ctr[t];
        if (v == m && v < ct) {
            int sp = atomicAdd(&lcnt, 1);   // LDS atomic, block-local
            if (sp < MAXPB) { lval[sp] = v; lidx[sp] = (y0 + t) * WW + x; }
        }
    }
    __syncthreads();

    int bkt = blockIdx.y * gridDim.x + blockIdx.x;
    int cnt = min(lcnt, MAXPB);
    if (tid == 0) counts[bkt] = cnt;
    for (int i = tid; i < cnt; i += 256) {
        gcv[bkt * MAXPB + i] = lval[i];
        gci[bkt * MAXPB + i] = lidx[i];
    }
}

// Bucket compaction (pair-compressed scan over 512 buckets) + replicated
// selection (cheap when M small) + instance assignment.
__global__ __launch_bounds__(256) void inst_select_kernel(const float* __restrict__ fg,
                                                          const float* __restrict__ cr,
                                                          const float* __restrict__ gcv,
                                                          const int* __restrict__ gci,
                                                          const int* __restrict__ counts,
                                                          float* __restrict__ out) {
    __shared__ int s_pre[256];
    __shared__ float s_cv[CAP];
    __shared__ int s_ci[CAP];
    __shared__ float bv[256];
    __shared__ int bi[256];
    __shared__ int s_idx[TOPK];
    __shared__ float s_val[TOPK];
    __shared__ float s_selx[TOPK];
    __shared__ float s_sely[TOPK];
    const int tid = threadIdx.x;

    // ---- compact buckets into LDS: each thread owns 2 buckets ----
    int c0 = counts[2 * tid];
    int c1 = counts[2 * tid + 1];
    s_pre[tid] = c0 + c1;
    __syncthreads();
    #pragma unroll
    for (int off = 1; off < 256; off <<= 1) {
        int add = (tid >= off) ? s_pre[tid - off] : 0;
        __syncthreads();
        s_pre[tid] += add;
        __syncthreads();
    }
    int total = s_pre[255];
    int M = min(total, CAP);
    int inc = s_pre[tid];
    int base0 = inc - c0 - c1;
    int base1 = inc - c1;
    for (int j = 0; j < c0; ++j) {
        int p = base0 + j;
        if (p < CAP) { s_cv[p] = gcv[(2 * tid) * MAXPB + j]; s_ci[p] = gci[(2 * tid) * MAXPB + j]; }
    }
    for (int j = 0; j < c1; ++j) {
        int p = base1 + j;
        if (p < CAP) { s_cv[p] = gcv[(2 * tid + 1) * MAXPB + j]; s_ci[p] = gci[(2 * tid + 1) * MAXPB + j]; }
    }
    __syncthreads();

    const int Mtop = (M < TOPK) ? M : TOPK;

    // k-th smallest by (val, idx) lexicographic = min over entries strictly
    // greater than the previous pick (matches jax top_k tie-break).
    float lastv = -INFINITY;
    int lasti = -1;
    for (int k = 0; k < Mtop; ++k) {
        float bestv = INFINITY;
        int besti = 0x7fffffff;
        for (int j = tid; j < M; j += 256) {
            float cvj = s_cv[j];
            int cij = s_ci[j];
            if (cvj > lastv || (cvj == lastv && cij > lasti)) {
                if (cvj < bestv || (cvj == bestv && cij < besti)) { bestv = cvj; besti = cij; }
            }
        }
        bv[tid] = bestv; bi[tid] = besti;
        __syncthreads();
        for (int s = 128; s > 0; s >>= 1) {
            if (tid < s) {
                float ov = bv[tid + s]; int oi = bi[tid + s];
                if (ov < bv[tid] || (ov == bv[tid] && oi < bi[tid])) { bv[tid] = ov; bi[tid] = oi; }
            }
            __syncthreads();
        }
        lastv = bv[0]; lasti = bi[0];
        if (tid == 0) { s_val[k] = lastv; s_idx[k] = lasti; }
        __syncthreads();
    }

    // Parallel fill of remaining slots with smallest non-candidate indices
    // (non-candidates tie at -inf in top_k(-cand): ascending index).
    // rank r non-candidate index = fixed point of g = r + #{ci <= g}.
    for (int k = Mtop + tid; k < TOPK; k += 256) {
        int r = k - Mtop;
        int g = r, prev = -1;
        while (g != prev) {
            prev = g;
            int cnt2 = 0;
            for (int j = 0; j < M; ++j) cnt2 += (s_ci[j] <= g) ? 1 : 0;
            g = r + cnt2;
        }
        s_idx[k] = g;
        s_val[k] = INFINITY;
    }
    __syncthreads();

    for (int k = tid; k < TOPK; k += 256) {
        int idx = s_idx[k];
        s_sely[k] = (float)(idx >> 10);       // idx / W
        s_selx[k] = (float)(idx & (WW - 1));  // idx % W
    }
    __syncthreads();

    // block 0 writes coords + cerr outputs
    if (blockIdx.x == 0) {
        for (int k = tid; k < TOPK; k += 256) {
            out[HH * WW + 2 * k]     = s_sely[k];
            out[HH * WW + 2 * k + 1] = s_selx[k];
            out[HH * WW + 2 * TOPK + k] = (k < Mtop) ? s_val[k] : 0.0f;
        }
    }

    // ---- instance assignment: 4 pixels per thread, float4 I/O ----
    int idx4 = blockIdx.x * 256 + tid;     // float4 index
    float4 o = make_float4(0.f, 0.f, 0.f, 0.f);
    if (M > 0) {
        int pix0 = idx4 * 4;
        int y = pix0 >> 10;
        float4 f = ((const float4*)fg)[idx4];
        float4 cx0 = ((const float4*)cr)[idx4];
        float4 cy0 = ((const float4*)(cr + HH * WW))[idx4];
        float fgv[4] = {f.x, f.y, f.z, f.w};
        float crx[4] = {cx0.x, cx0.y, cx0.z, cx0.w};
        float cry[4] = {cy0.x, cy0.y, cy0.z, cy0.w};
        float res[4];
        #pragma unroll
        for (int t = 0; t < 4; ++t) {
            res[t] = 0.f;
            if (fgv[t] >= 0.5f) {
                int x = (pix0 + t) & (WW - 1);
                float px = (float)(x + 1) - crx[t];
                float py = (float)(y + 1) - cry[t];
                float best = INFINITY;
                int bk = 0;
                for (int k = 0; k < Mtop; ++k) {
                    float ddx = px - s_selx[k];
                    float ddy = py - s_sely[k];
                    float d = ddx * ddx + ddy * ddy;
                    if (d < best) { best = d; bk = k; }  // first-occurrence
                }
                res[t] = (float)(bk + 1);
            }
        }
        o = make_float4(res[0], res[1], res[2], res[3]);
    }
    ((float4*)out)[idx4] = o;
}

extern "C" void kernel_launch(void* const* d_in, const int* in_sizes, int n_in,
                              void* d_out, int out_size, void* d_ws, size_t ws_size,
                              hipStream_t stream) {
    const float* fg = (const float*)d_in[0];
    const float* cr = (const float*)d_in[1];
    float* out = (float*)d_out;

    char* ws = (char*)d_ws;
    int* counts = (int*)ws;
    float* vote = (float*)(ws + 2048);
    float* gcv = (float*)(ws + 2048 + 4 * HH * WW);
    int* gci = (int*)(ws + 2048 + 4 * HH * WW + 4 * NBUCK * MAXPB);

    // CENTER_THRESH = mean circle distance + 0.5
    double s = 0.0;
    int n = 0;
    for (int iy = 0; iy < KK; ++iy)
        for (int ix = 0; ix < KK; ++ix) {
            double dx = ix - RR, dy = iy - RR;
            double d = sqrt(dx * dx + dy * dy);
            if (d <= (double)RR) { s += d; n++; }
        }
    float ct = (float)(s / n + 0.5);

    dim3 vgrid(WW / BW, HH / BH);        // 16 x 64 = 1024 blocks
    vote_kernel<<<vgrid, 256, 0, stream>>>(cr, vote);
    dim3 ngrid(WW / 64, HH / 16);        // 16 x 32 = 512 blocks
    nms_kernel<<<ngrid, 256, 0, stream>>>(vote, gcv, gci, counts, ct);
    inst_select_kernel<<<(HH * WW / 4) / 256, 256, 0, stream>>>(fg, cr, gcv, gci, counts, out);
}

// Round 12
// 24.050 us; speedup vs baseline: 3.8195x; 1.0489x over previous
//
#include <hip/hip_runtime.h>
#include <math.h>

#define HH 512
#define WW 1024
#define RR 5
#define KK 11
#define TOPK 200
#define MAXC 16384

// ---- vote tile: 64 wide x 8 tall, 256 threads, 2 output rows per thread
// grid 1024 blocks = 4 blocks/CU (r10 measured: 9.4 us hot, VALUBusy 80%)
#define BW 64
#define BH 8
#define TT 2
#define SROWS (BH + 10)   // 18 staged rows
#define SCOLS (BW + 10)   // 74 staged cols

// ws layout (bytes):
// [0..63]          : meta ints: meta[0]=cnt
// [64 ..)          : vote float[H*W]
// [64+4*HW ..)     : cv float[MAXC]
// [.. +4*MAXC ..)  : ci int[MAXC]

__global__ __launch_bounds__(256) void vote_kernel(const float* __restrict__ cr,
                                                   float* __restrict__ vote,
                                                   int* __restrict__ meta) {
    __shared__ float2 s[SROWS][SCOLS + 2];   // row stride 76 float2
    const int tid = threadIdx.x;
    const int bx = blockIdx.x * BW, by = blockIdx.y * BH;

    if (bx == 0 && by == 0 && tid < 4) meta[tid] = 0;   // re-zeroed every launch

    // Stage cr (18 x 74) region, origin (by-5, bx-5), zero-padded.
    for (int l = tid; l < SROWS * SCOLS; l += 256) {
        int r = l / SCOLS, c = l % SCOLS;
        int gy = by - 5 + r, gx = bx - 5 + c;
        bool ok = (gy >= 0) && (gy < HH) && (gx >= 0) && (gx < WW);
        float vx = ok ? cr[gy * WW + gx] : 0.0f;
        float vy = ok ? cr[HH * WW + gy * WW + gx] : 0.0f;
        s[r][c] = make_float2(vx, vy);
    }
    __syncthreads();

    const int x = tid & 63;        // 0..63 within tile
    const int yt = tid >> 6;       // 0..3 -> output rows yt*2, yt*2+1
    // 2 accumulator chains per output row (reassociated sum: safe — vote
    // perturbation ~1e-5 vs ~0.3 margin to CENTER_THRESH; NMS equality only
    // compares values computed with identical op order across all blocks).
    float a[TT] = {0.f, 0.f};
    float b[TT] = {0.f, 0.f};

    #pragma unroll
    for (int rr = 0; rr < TT + 10; ++rr) {          // staged row offset 0..11
        #pragma unroll
        for (int ix = 0; ix < KK; ++ix) {
            const int ox = ix - 5;
            bool any = false;
            #pragma unroll
            for (int t = 0; t < TT; ++t) {
                const int oy = rr - 5 - t;
                if (oy >= -RR && oy <= RR && ox * ox + oy * oy <= RR * RR) any = true;
            }
            if (!any) continue;                      // compile-time elision
            float2 v = s[yt * TT + rr][x + ix];
            float dx = (float)ox - v.x;              // dx^2 CSE'd across t
            float dx2 = dx * dx;
            #pragma unroll
            for (int t = 0; t < TT; ++t) {
                const int oy = rr - 5 - t;
                if (oy >= -RR && oy <= RR && ox * ox + oy * oy <= RR * RR) {
                    float dy = (float)oy - v.y;
                    float sv = __builtin_amdgcn_sqrtf(fmaf(dy, dy, dx2));
                    if (ix & 1) b[t] += sv; else a[t] += sv;
                }
            }
        }
    }
    const int y0 = by + yt * TT;
    #pragma unroll
    for (int t = 0; t < TT; ++t)
        vote[(y0 + t) * WW + bx + x] = (a[t] + b[t]) / 81.0f + 1.0f;
}

// Separable 7x7 min-pool NMS: each thread owns 4 pixels in a column.
// 10 row-mins shared across the 4 outputs; index-clamp == inf-padding
// (duplicated edge values are members of the true window, can't change min).
// Candidate order via global atomic is non-deterministic, but selection is
// order-independent (lexicographic multiset extraction) -> output stable.
__global__ __launch_bounds__(256) void nms_kernel(const float* __restrict__ vote,
                                                  float* __restrict__ cv, int* __restrict__ ci,
                                                  int* __restrict__ meta, float ct) {
    const int tid = threadIdx.x;
    const int x = blockIdx.x * 64 + (tid & 63);
    const int y0 = blockIdx.y * 16 + (tid >> 6) * 4;

    int xc[7];
    #pragma unroll
    for (int d = 0; d < 7; ++d) xc[d] = min(max(x + d - 3, 0), WW - 1);

    float r[10], c[4];
    #pragma unroll
    for (int j = 0; j < 10; ++j) {
        int yy = min(max(y0 + j - 3, 0), HH - 1);
        const float* row = vote + yy * WW;
        float m0 = fminf(row[xc[0]], row[xc[1]]);
        float m1 = fminf(row[xc[2]], row[xc[3]]);
        float m2 = fminf(row[xc[4]], row[xc[5]]);
        float m3 = row[xc[6]];
        if (j >= 3 && j < 7) c[j - 3] = row[xc[3]];   // center value (xc[3]==x)
        r[j] = fminf(fminf(m0, m1), fminf(m2, m3));
    }
    float p[9], q4[7];
    #pragma unroll
    for (int j = 0; j < 9; ++j) p[j] = fminf(r[j], r[j + 1]);
    #pragma unroll
    for (int j = 0; j < 7; ++j) q4[j] = fminf(p[j], p[j + 2]);
    #pragma unroll
    for (int t = 0; t < 4; ++t) {
        float m = fminf(q4[t], q4[t + 3]);
        float v = c[t];
        if (v == m && v < ct) {
            int s = atomicAdd(&meta[0], 1);
            if (s < MAXC) { cv[s] = v; ci[s] = (y0 + t) * WW + x; }
        }
    }
}

// Selection (replicated per block, cheap when M small) + instance assignment.
// Cross-kernel visibility of cv/ci/meta: same-stream kernel ordering.
__global__ __launch_bounds__(256) void inst_select_kernel(const float* __restrict__ fg,
                                                          const float* __restrict__ cr,
                                                          const float* __restrict__ cv,
                                                          const int* __restrict__ ci,
                                                          const int* __restrict__ meta,
                                                          float* __restrict__ out) {
    __shared__ float bv[256];
    __shared__ int bi[256];
    __shared__ int s_idx[TOPK];
    __shared__ float s_val[TOPK];
    __shared__ float s_selx[TOPK];
    __shared__ float s_sely[TOPK];
    const int tid = threadIdx.x;
    int M = meta[0];
    if (M > MAXC) M = MAXC;
    const int Mtop = (M < TOPK) ? M : TOPK;

    // k-th smallest by (val, idx) lexicographic = min over entries strictly
    // greater than the previous pick (matches jax top_k tie-break).
    float lastv = -INFINITY;
    int lasti = -1;
    for (int k = 0; k < Mtop; ++k) {
        float bestv = INFINITY;
        int besti = 0x7fffffff;
        for (int j = tid; j < M; j += 256) {
            float cvj = cv[j];
            int cij = ci[j];
            if (cvj > lastv || (cvj == lastv && cij > lasti)) {
                if (cvj < bestv || (cvj == bestv && cij < besti)) { bestv = cvj; besti = cij; }
            }
        }
        bv[tid] = bestv; bi[tid] = besti;
        __syncthreads();
        for (int s = 128; s > 0; s >>= 1) {
            if (tid < s) {
                float ov = bv[tid + s]; int oi = bi[tid + s];
                if (ov < bv[tid] || (ov == bv[tid] && oi < bi[tid])) { bv[tid] = ov; bi[tid] = oi; }
            }
            __syncthreads();
        }
        lastv = bv[0]; lasti = bi[0];
        if (tid == 0) { s_val[k] = lastv; s_idx[k] = lasti; }
        __syncthreads();
    }

    // Parallel fill of remaining slots with the smallest non-candidate
    // indices (non-candidates tie at -inf in top_k(-cand): ascending index).
    // rank r non-candidate index = fixed point of g = r + #{ci <= g}.
    for (int k = Mtop + tid; k < TOPK; k += 256) {
        int r = k - Mtop;
        int g = r, prev = -1;
        while (g != prev) {
            prev = g;
            int cnt = 0;
            for (int j = 0; j < M; ++j) cnt += (ci[j] <= g) ? 1 : 0;
            g = r + cnt;
        }
        s_idx[k] = g;
        s_val[k] = INFINITY;
    }
    __syncthreads();

    for (int k = tid; k < TOPK; k += 256) {
        int idx = s_idx[k];
        s_sely[k] = (float)(idx >> 10);       // idx / W
        s_selx[k] = (float)(idx & (WW - 1));  // idx % W
    }
    __syncthreads();

    // block 0 writes coords + cerr outputs
    if (blockIdx.x == 0) {
        for (int k = tid; k < TOPK; k += 256) {
            out[HH * WW + 2 * k]     = s_sely[k];
            out[HH * WW + 2 * k + 1] = s_selx[k];
            out[HH * WW + 2 * TOPK + k] = (k < Mtop) ? s_val[k] : 0.0f;
        }
    }

    // ---- instance assignment: 4 pixels per thread, float4 I/O ----
    int idx4 = blockIdx.x * 256 + tid;     // float4 index
    float4 o = make_float4(0.f, 0.f, 0.f, 0.f);
    if (M > 0) {
        int pix0 = idx4 * 4;
        int y = pix0 >> 10;
        float4 f = ((const float4*)fg)[idx4];
        float4 cx0 = ((const float4*)cr)[idx4];
        float4 cy0 = ((const float4*)(cr + HH * WW))[idx4];
        float fgv[4] = {f.x, f.y, f.z, f.w};
        float crx[4] = {cx0.x, cx0.y, cx0.z, cx0.w};
        float cry[4] = {cy0.x, cy0.y, cy0.z, cy0.w};
        float res[4];
        #pragma unroll
        for (int t = 0; t < 4; ++t) {
            res[t] = 0.f;
            if (fgv[t] >= 0.5f) {
                int x = (pix0 + t) & (WW - 1);
                float px = (float)(x + 1) - crx[t];
                float py = (float)(y + 1) - cry[t];
                float best = INFINITY;
                int bk = 0;
                for (int k = 0; k < Mtop; ++k) {
                    float ddx = px - s_selx[k];
                    float ddy = py - s_sely[k];
                    float d = ddx * ddx + ddy * ddy;
                    if (d < best) { best = d; bk = k; }  // first-occurrence
                }
                res[t] = (float)(bk + 1);
            }
        }
        o = make_float4(res[0], res[1], res[2], res[3]);
    }
    ((float4*)out)[idx4] = o;
}

extern "C" void kernel_launch(void* const* d_in, const int* in_sizes, int n_in,
                              void* d_out, int out_size, void* d_ws, size_t ws_size,
                              hipStream_t stream) {
    const float* fg = (const float*)d_in[0];
    const float* cr = (const float*)d_in[1];
    float* out = (float*)d_out;

    char* ws = (char*)d_ws;
    int* meta = (int*)ws;
    float* vote = (float*)(ws + 64);
    float* cv = (float*)(ws + 64 + 4 * HH * WW);
    int* ci = (int*)(ws + 64 + 4 * HH * WW + 4 * MAXC);

    // CENTER_THRESH = mean circle distance + 0.5
    double s = 0.0;
    int n = 0;
    for (int iy = 0; iy < KK; ++iy)
        for (int ix = 0; ix < KK; ++ix) {
            double dx = ix - RR, dy = iy - RR;
            double d = sqrt(dx * dx + dy * dy);
            if (d <= (double)RR) { s += d; n++; }
        }
    float ct = (float)(s / n + 0.5);

    dim3 vgrid(WW / BW, HH / BH);        // 16 x 64 = 1024 blocks
    vote_kernel<<<vgrid, 256, 0, stream>>>(cr, vote, meta);
    dim3 ngrid(WW / 64, HH / 16);        // 16 x 32 = 512 blocks
    nms_kernel<<<ngrid, 256, 0, stream>>>(vote, cv, ci, meta, ct);
    inst_select_kernel<<<(HH * WW / 4) / 256, 256, 0, stream>>>(fg, cr, cv, ci, meta, out);
}

// Round 13
// 22.393 us; speedup vs baseline: 4.1023x; 1.0740x over previous
//
#include <hip/hip_runtime.h>
#include <math.h>

#define HH 512
#define WW 1024
#define RR 5
#define KK 11
#define TOPK 200
#define MAXC 16384

// ---- vote tile: 64 wide x 16 tall, 256 threads, 4 output rows per thread
// Grid 16x32 = 512 blocks — IDENTICAL to nms grid (vote block k's output is
// read back by nms block k: same CU/XCD, L2-hot handoff). r6-verified 22.47.
#define BW 64
#define BH 16
#define TT 4
#define SROWS (BH + 10)   // 26 staged rows
#define SCOLS (BW + 10)   // 74 staged cols

// ws layout (bytes):
// [0..63]          : meta ints: meta[0]=cnt
// [64 ..)          : vote float[H*W]
// [64+4*HW ..)     : cv float[MAXC]
// [.. +4*MAXC ..)  : ci int[MAXC]

__global__ __launch_bounds__(256) void vote_kernel(const float* __restrict__ cr,
                                                   float* __restrict__ vote,
                                                   int* __restrict__ meta) {
    __shared__ float2 s[SROWS][SCOLS + 2];   // row stride 76 float2
    const int tid = threadIdx.x;
    const int bx = blockIdx.x * BW, by = blockIdx.y * BH;

    if (bx == 0 && by == 0 && tid < 4) meta[tid] = 0;   // re-zeroed every launch

    // Stage cr (26 x 74) region, origin (by-5, bx-5), zero-padded.
    for (int l = tid; l < SROWS * SCOLS; l += 256) {
        int r = l / SCOLS, c = l % SCOLS;
        int gy = by - 5 + r, gx = bx - 5 + c;
        bool ok = (gy >= 0) && (gy < HH) && (gx >= 0) && (gx < WW);
        float vx = ok ? cr[gy * WW + gx] : 0.0f;
        float vy = ok ? cr[HH * WW + gy * WW + gx] : 0.0f;
        s[r][c] = make_float2(vx, vy);
    }
    __syncthreads();

    const int x = tid & 63;        // 0..63 within tile
    const int yt = tid >> 6;       // 0..3 -> output rows yt*4 .. yt*4+3
    // 2 accumulator chains per output row (reassociated sum: safe — vote
    // perturbation ~1e-5 vs ~0.3 margin to CENTER_THRESH; NMS equality only
    // compares values computed with identical op order across all blocks).
    float a[TT] = {0.f, 0.f, 0.f, 0.f};
    float b[TT] = {0.f, 0.f, 0.f, 0.f};

    #pragma unroll
    for (int rr = 0; rr < TT + 10; ++rr) {          // staged row offset 0..13
        #pragma unroll
        for (int ix = 0; ix < KK; ++ix) {
            const int ox = ix - 5;
            bool any = false;
            #pragma unroll
            for (int t = 0; t < TT; ++t) {
                const int oy = rr - 5 - t;
                if (oy >= -RR && oy <= RR && ox * ox + oy * oy <= RR * RR) any = true;
            }
            if (!any) continue;                      // compile-time elision
            float2 v = s[yt * TT + rr][x + ix];
            float dx = (float)ox - v.x;              // dx^2 CSE'd across t
            float dx2 = dx * dx;
            #pragma unroll
            for (int t = 0; t < TT; ++t) {
                const int oy = rr - 5 - t;
                if (oy >= -RR && oy <= RR && ox * ox + oy * oy <= RR * RR) {
                    float dy = (float)oy - v.y;
                    float sv = __builtin_amdgcn_sqrtf(fmaf(dy, dy, dx2));
                    if (ix & 1) b[t] += sv; else a[t] += sv;
                }
            }
        }
    }
    const int y0 = by + yt * TT;
    #pragma unroll
    for (int t = 0; t < TT; ++t)
        vote[(y0 + t) * WW + bx + x] = (a[t] + b[t]) / 81.0f + 1.0f;
}

// Separable 7x7 min-pool NMS: each thread owns 4 pixels in a column.
// 10 row-mins shared across the 4 outputs; index-clamp == inf-padding
// (duplicated edge values are members of the true window, can't change min).
// Candidate order via global atomic is non-deterministic, but selection is
// order-independent (lexicographic multiset extraction) -> output stable.
__global__ __launch_bounds__(256) void nms_kernel(const float* __restrict__ vote,
                                                  float* __restrict__ cv, int* __restrict__ ci,
                                                  int* __restrict__ meta, float ct) {
    const int tid = threadIdx.x;
    const int x = blockIdx.x * 64 + (tid & 63);
    const int y0 = blockIdx.y * 16 + (tid >> 6) * 4;

    int xc[7];
    #pragma unroll
    for (int d = 0; d < 7; ++d) xc[d] = min(max(x + d - 3, 0), WW - 1);

    float r[10], c[4];
    #pragma unroll
    for (int j = 0; j < 10; ++j) {
        int yy = min(max(y0 + j - 3, 0), HH - 1);
        const float* row = vote + yy * WW;
        float m0 = fminf(row[xc[0]], row[xc[1]]);
        float m1 = fminf(row[xc[2]], row[xc[3]]);
        float m2 = fminf(row[xc[4]], row[xc[5]]);
        float m3 = row[xc[6]];
        if (j >= 3 && j < 7) c[j - 3] = row[xc[3]];   // center value (xc[3]==x)
        r[j] = fminf(fminf(m0, m1), fminf(m2, m3));
    }
    float p[9], q4[7];
    #pragma unroll
    for (int j = 0; j < 9; ++j) p[j] = fminf(r[j], r[j + 1]);
    #pragma unroll
    for (int j = 0; j < 7; ++j) q4[j] = fminf(p[j], p[j + 2]);
    #pragma unroll
    for (int t = 0; t < 4; ++t) {
        float m = fminf(q4[t], q4[t + 3]);
        float v = c[t];
        if (v == m && v < ct) {
            int s = atomicAdd(&meta[0], 1);
            if (s < MAXC) { cv[s] = v; ci[s] = (y0 + t) * WW + x; }
        }
    }
}

// Selection (replicated per block, cheap when M small) + instance assignment.
// Cross-kernel visibility of cv/ci/meta: same-stream kernel ordering.
__global__ __launch_bounds__(256) void inst_select_kernel(const float* __restrict__ fg,
                                                          const float* __restrict__ cr,
                                                          const float* __restrict__ cv,
                                                          const int* __restrict__ ci,
                                                          const int* __restrict__ meta,
                                                          float* __restrict__ out) {
    __shared__ float bv[256];
    __shared__ int bi[256];
    __shared__ int s_idx[TOPK];
    __shared__ float s_val[TOPK];
    __shared__ float s_selx[TOPK];
    __shared__ float s_sely[TOPK];
    const int tid = threadIdx.x;
    int M = meta[0];
    if (M > MAXC) M = MAXC;
    const int Mtop = (M < TOPK) ? M : TOPK;

    // k-th smallest by (val, idx) lexicographic = min over entries strictly
    // greater than the previous pick (matches jax top_k tie-break).
    float lastv = -INFINITY;
    int lasti = -1;
    for (int k = 0; k < Mtop; ++k) {
        float bestv = INFINITY;
        int besti = 0x7fffffff;
        for (int j = tid; j < M; j += 256) {
            float cvj = cv[j];
            int cij = ci[j];
            if (cvj > lastv || (cvj == lastv && cij > lasti)) {
                if (cvj < bestv || (cvj == bestv && cij < besti)) { bestv = cvj; besti = cij; }
            }
        }
        bv[tid] = bestv; bi[tid] = besti;
        __syncthreads();
        for (int s = 128; s > 0; s >>= 1) {
            if (tid < s) {
                float ov = bv[tid + s]; int oi = bi[tid + s];
                if (ov < bv[tid] || (ov == bv[tid] && oi < bi[tid])) { bv[tid] = ov; bi[tid] = oi; }
            }
            __syncthreads();
        }
        lastv = bv[0]; lasti = bi[0];
        if (tid == 0) { s_val[k] = lastv; s_idx[k] = lasti; }
        __syncthreads();
    }

    // Parallel fill of remaining slots with the smallest non-candidate
    // indices (non-candidates tie at -inf in top_k(-cand): ascending index).
    // rank r non-candidate index = fixed point of g = r + #{ci <= g}.
    for (int k = Mtop + tid; k < TOPK; k += 256) {
        int r = k - Mtop;
        int g = r, prev = -1;
        while (g != prev) {
            prev = g;
            int cnt = 0;
            for (int j = 0; j < M; ++j) cnt += (ci[j] <= g) ? 1 : 0;
            g = r + cnt;
        }
        s_idx[k] = g;
        s_val[k] = INFINITY;
    }
    __syncthreads();

    for (int k = tid; k < TOPK; k += 256) {
        int idx = s_idx[k];
        s_sely[k] = (float)(idx >> 10);       // idx / W
        s_selx[k] = (float)(idx & (WW - 1));  // idx % W
    }
    __syncthreads();

    // block 0 writes coords + cerr outputs
    if (blockIdx.x == 0) {
        for (int k = tid; k < TOPK; k += 256) {
            out[HH * WW + 2 * k]     = s_sely[k];
            out[HH * WW + 2 * k + 1] = s_selx[k];
            out[HH * WW + 2 * TOPK + k] = (k < Mtop) ? s_val[k] : 0.0f;
        }
    }

    // ---- instance assignment: 4 pixels per thread, float4 I/O ----
    int idx4 = blockIdx.x * 256 + tid;     // float4 index
    float4 o = make_float4(0.f, 0.f, 0.f, 0.f);
    if (M > 0) {
        int pix0 = idx4 * 4;
        int y = pix0 >> 10;
        float4 f = ((const float4*)fg)[idx4];
        float4 cx0 = ((const float4*)cr)[idx4];
        float4 cy0 = ((const float4*)(cr + HH * WW))[idx4];
        float fgv[4] = {f.x, f.y, f.z, f.w};
        float crx[4] = {cx0.x, cx0.y, cx0.z, cx0.w};
        float cry[4] = {cy0.x, cy0.y, cy0.z, cy0.w};
        float res[4];
        #pragma unroll
        for (int t = 0; t < 4; ++t) {
            res[t] = 0.f;
            if (fgv[t] >= 0.5f) {
                int x = (pix0 + t) & (WW - 1);
                float px = (float)(x + 1) - crx[t];
                float py = (float)(y + 1) - cry[t];
                float best = INFINITY;
                int bk = 0;
                for (int k = 0; k < Mtop; ++k) {
                    float ddx = px - s_selx[k];
                    float ddy = py - s_sely[k];
                    float d = ddx * ddx + ddy * ddy;
                    if (d < best) { best = d; bk = k; }  // first-occurrence
                }
                res[t] = (float)(bk + 1);
            }
        }
        o = make_float4(res[0], res[1], res[2], res[3]);
    }
    ((float4*)out)[idx4] = o;
}

extern "C" void kernel_launch(void* const* d_in, const int* in_sizes, int n_in,
                              void* d_out, int out_size, void* d_ws, size_t ws_size,
                              hipStream_t stream) {
    const float* fg = (const float*)d_in[0];
    const float* cr = (const float*)d_in[1];
    float* out = (float*)d_out;

    char* ws = (char*)d_ws;
    int* meta = (int*)ws;
    float* vote = (float*)(ws + 64);
    float* cv = (float*)(ws + 64 + 4 * HH * WW);
    int* ci = (int*)(ws + 64 + 4 * HH * WW + 4 * MAXC);

    // CENTER_THRESH = mean circle distance + 0.5
    double s = 0.0;
    int n = 0;
    for (int iy = 0; iy < KK; ++iy)
        for (int ix = 0; ix < KK; ++ix) {
            double dx = ix - RR, dy = iy - RR;
            double d = sqrt(dx * dx + dy * dy);
            if (d <= (double)RR) { s += d; n++; }
        }
    float ct = (float)(s / n + 0.5);

    dim3 vgrid(WW / BW, HH / BH);        // 16 x 32 = 512 blocks (matches nms)
    vote_kernel<<<vgrid, 256, 0, stream>>>(cr, vote, meta);
    dim3 ngrid(WW / 64, HH / 16);        // 16 x 32 = 512 blocks
    nms_kernel<<<ngrid, 256, 0, stream>>>(vote, cv, ci, meta, ct);
    inst_select_kernel<<<(HH * WW / 4) / 256, 256, 0, stream>>>(fg, cr, cv, ci, meta, out);
}